// Round 5
// baseline (370.329 us; speedup 1.0000x reference)
//
#include <hip/hip_runtime.h>
#include <hip/hip_fp16.h>

#define SEQ    2048
#define DIN    2048
#define DOUT   2048
#define NH     32
#define NKV    8
#define HD     64
#define BB     2

typedef _Float16 half_t;
typedef __attribute__((ext_vector_type(8))) _Float16 half8;
typedef __attribute__((ext_vector_type(4))) _Float16 half4;
typedef __attribute__((ext_vector_type(2))) __fp16   fp16x2;   // cvt_pkrtz native type
typedef __attribute__((ext_vector_type(4))) float    floatx4;

union H8U { half8 h; int u[4]; };
union H2I { fp16x2 h; int i; };

// async 16B global->LDS (wave-uniform LDS base + lane*16)
__device__ __forceinline__ void gload16(void* l, const void* g) {
    __builtin_amdgcn_global_load_lds(
        (const __attribute__((address_space(1))) void*)g,
        (__attribute__((address_space(3))) void*)l, 16, 0, 0);
}

// ---------------------------------------------------------------- cast f32->f16
__global__ void cast_f2h(const float* __restrict__ in, half_t* __restrict__ out, int n4) {
    int i = blockIdx.x * blockDim.x + threadIdx.x;
    if (i < n4) {
        float4 v = ((const float4*)in)[i];
        half4 h;
        h[0] = (half_t)v.x; h[1] = (half_t)v.y; h[2] = (half_t)v.z; h[3] = (half_t)v.w;
        ((half4*)out)[i] = h;
    }
}

// ---------------------------------------------------------------- transpose+cast: f32 [Kd][Nd] -> f16 [Nd][Kd]
__global__ __launch_bounds__(256) void tcast(const float* __restrict__ in, half_t* __restrict__ out,
                                             int Kd, int Nd) {
    __shared__ float T[32][33];
    int x0 = blockIdx.x * 32, y0 = blockIdx.y * 32;
    int tx = threadIdx.x & 31, ty = threadIdx.x >> 5;
    #pragma unroll
    for (int j = 0; j < 4; j++)
        T[ty + j * 8][tx] = in[(size_t)(y0 + ty + j * 8) * Nd + x0 + tx];
    __syncthreads();
    #pragma unroll
    for (int j = 0; j < 4; j++)
        out[(size_t)(x0 + ty + j * 8) * Kd + y0 + tx] = (half_t)T[tx][ty + j * 8];
}

// ---------------------------------------------------------------- fused QKV GEMM + RoPE + relayout
// C = xh[4096x2048] @ WqkvT[3072x2048]^T ; epilogue routes each wave's 64-col head:
//   cols <2048  : RoPE + scale(0.125*log2e) -> Qh [b][h][s][64]
//   2048..2559  : RoPE                      -> Kh [b][g][s][64]
//   2560..3071  : transpose                 -> Vt [b][g][d][SEQ]
__global__ __launch_bounds__(256) void gemm_qkv(
    const half_t* __restrict__ A, const half_t* __restrict__ Bt,
    const float* __restrict__ cosb, const float* __restrict__ sinb,
    half_t* __restrict__ Qh, half_t* __restrict__ Kh, half_t* __restrict__ Vt)
{
    __shared__ half_t As[4096];
    __shared__ half_t Bs[4096];
    const int K = DIN, M = BB * SEQ;
    int tid = threadIdx.x, wave = tid >> 6, lane = tid & 63;
    int quad = lane >> 4, l15 = lane & 15;
    int m0 = blockIdx.y * 128, n0 = blockIdx.x * 128;
    int wm = (wave >> 1) * 64, wn = (wave & 1) * 64;
    floatx4 acc[4][4] = {};

    int srow[2], skoff[2], sldso[2];
    #pragma unroll
    for (int is = 0; is < 2; is++) {
        int s = is * 256 + tid;
        int p = s >> 3, sc = s & 7;
        int c = sc ^ (p & 7);
        srow[is]  = 2 * p + (c >> 2);
        skoff[is] = (c & 3) * 8;
        sldso[is] = (is * 256 + wave * 64) * 8;
    }
    for (int k0 = 0; k0 < K; k0 += 32) {
        __syncthreads();
        #pragma unroll
        for (int is = 0; is < 2; is++) {
            gload16(&As[sldso[is]], A  + (size_t)(m0 + srow[is]) * K + k0 + skoff[is]);
            gload16(&Bs[sldso[is]], Bt + (size_t)(n0 + srow[is]) * K + k0 + skoff[is]);
        }
        __syncthreads();
        half8 af[4], bf[4];
        #pragma unroll
        for (int i = 0; i < 4; i++) {
            int r = wm + i * 16 + l15, p = r >> 1;
            int sc = (((r & 1) * 4 + quad) ^ (p & 7));
            af[i] = *(const half8*)&As[p * 64 + sc * 8];
            int rn = wn + i * 16 + l15, pn = rn >> 1;
            int scn = (((rn & 1) * 4 + quad) ^ (pn & 7));
            bf[i] = *(const half8*)&Bs[pn * 64 + scn * 8];
        }
        #pragma unroll
        for (int i = 0; i < 4; i++)
            #pragma unroll
            for (int j = 0; j < 4; j++)
                acc[i][j] = __builtin_amdgcn_mfma_f32_16x16x32_f16(af[i], bf[j], acc[i][j], 0, 0, 0);
    }

    // -------- epilogue: wave-uniform head routing
    const int headg = (n0 + wn) >> 6;          // 0..47
    const int b = m0 >> 11;                    // block never straddles batch
    const int s_base = (m0 & 2047) + wm + quad * 4;

    if (headg < 40) {                          // Q or K: RoPE
        const bool isQ = headg < 32;
        const float sc = isQ ? 0.125f * 1.44269504088896f : 1.0f;
        half_t* outp = isQ ? (Qh + (size_t)(b * NH + headg) * SEQ * 64)
                           : (Kh + (size_t)(b * NKV + (headg - 32)) * SEQ * 64);
        #pragma unroll
        for (int i = 0; i < 4; i++)
            #pragma unroll
            for (int r = 0; r < 4; r++) {
                int s = s_base + i * 16 + r;
                #pragma unroll
                for (int j = 0; j < 2; j++) {
                    int d = j * 16 + l15;
                    float x1 = acc[i][j][r], x2 = acc[i][j + 2][r];
                    float c1 = cosb[s * 64 + d],      s1 = sinb[s * 64 + d];
                    float c2 = cosb[s * 64 + d + 32], s2 = sinb[s * 64 + d + 32];
                    outp[(size_t)s * 64 + d]      = (half_t)((x1 * c1 - x2 * s1) * sc);
                    outp[(size_t)s * 64 + d + 32] = (half_t)((x2 * c2 + x1 * s2) * sc);
                }
            }
    } else {                                   // V: transpose to [d][s]
        half_t* vtp = Vt + (size_t)(b * NKV + (headg - 40)) * 64 * SEQ;
        #pragma unroll
        for (int i = 0; i < 4; i++) {
            int s = s_base + i * 16;
            #pragma unroll
            for (int j = 0; j < 4; j++) {
                int d = j * 16 + l15;
                half4 hv;
                hv[0] = (half_t)acc[i][j][0];
                hv[1] = (half_t)acc[i][j][1];
                hv[2] = (half_t)acc[i][j][2];
                hv[3] = (half_t)acc[i][j][3];
                *(half4*)(vtp + (size_t)d * SEQ + s) = hv;
            }
        }
    }
}

// ---------------------------------------------------------------- GEMM (m97 structure), f32 out
__global__ __launch_bounds__(256) void gemm_tn_f(
    const half_t* __restrict__ A, const half_t* __restrict__ Bt,
    float* __restrict__ C, int M, int N, int K)
{
    __shared__ half_t As[4096];
    __shared__ half_t Bs[4096];
    int tid = threadIdx.x, wave = tid >> 6, lane = tid & 63;
    int quad = lane >> 4, l15 = lane & 15;
    int m0 = blockIdx.y * 128, n0 = blockIdx.x * 128;
    int wm = (wave >> 1) * 64, wn = (wave & 1) * 64;
    floatx4 acc[4][4] = {};
    int srow[2], skoff[2], sldso[2];
    #pragma unroll
    for (int is = 0; is < 2; is++) {
        int s = is * 256 + tid;
        int p = s >> 3, sc = s & 7;
        int c = sc ^ (p & 7);
        srow[is]  = 2 * p + (c >> 2);
        skoff[is] = (c & 3) * 8;
        sldso[is] = (is * 256 + wave * 64) * 8;
    }
    for (int k0 = 0; k0 < K; k0 += 32) {
        __syncthreads();
        #pragma unroll
        for (int is = 0; is < 2; is++) {
            gload16(&As[sldso[is]], A  + (size_t)(m0 + srow[is]) * K + k0 + skoff[is]);
            gload16(&Bs[sldso[is]], Bt + (size_t)(n0 + srow[is]) * K + k0 + skoff[is]);
        }
        __syncthreads();
        half8 af[4], bf[4];
        #pragma unroll
        for (int i = 0; i < 4; i++) {
            int r = wm + i * 16 + l15, p = r >> 1;
            int sc = (((r & 1) * 4 + quad) ^ (p & 7));
            af[i] = *(const half8*)&As[p * 64 + sc * 8];
            int rn = wn + i * 16 + l15, pn = rn >> 1;
            int scn = (((rn & 1) * 4 + quad) ^ (pn & 7));
            bf[i] = *(const half8*)&Bs[pn * 64 + scn * 8];
        }
        #pragma unroll
        for (int i = 0; i < 4; i++)
            #pragma unroll
            for (int j = 0; j < 4; j++)
                acc[i][j] = __builtin_amdgcn_mfma_f32_16x16x32_f16(af[i], bf[j], acc[i][j], 0, 0, 0);
    }
    #pragma unroll
    for (int i = 0; i < 4; i++) {
        int row = m0 + wm + i * 16 + quad * 4;
        #pragma unroll
        for (int j = 0; j < 4; j++) {
            int col = n0 + wn + j * 16 + l15;
            #pragma unroll
            for (int r = 0; r < 4; r++)
                C[(size_t)(row + r) * N + col] = acc[i][j][r];
        }
    }
}

// ---------------------------------------------------------------- causal GQA flash attention (S^T layout)
// 256 thr = 4 waves; 128 queries/block; 64-key tiles, double-buffered async staging.
// Q pre-scaled by 0.125*log2e -> softmax in base-2 (exp2f).
__global__ __launch_bounds__(256, 4) void attn(
    const half_t* __restrict__ Qh, const half_t* __restrict__ Kh,
    const half_t* __restrict__ Vt, half_t* __restrict__ ctx)
{
    __shared__ half_t Ks[2][4096];
    __shared__ half_t Vs[2][4096];

    const int tid = threadIdx.x, wave = tid >> 6, lane = tid & 63;
    const int quad = lane >> 4, l15 = lane & 15;
    const int bid = blockIdx.x;
    const int qt = 15 - (bid >> 6);      // longest blocks first
    const int b  = (bid >> 5) & 1;
    const int h  = bid & 31;
    const int g  = h >> 2;
    const int q0 = qt * 128;
    const int wm = wave * 32;

    const half_t* kp = Kh + (size_t)(b * NKV + g) * SEQ * 64;
    const half_t* vp = Vt + (size_t)(b * NKV + g) * 64 * SEQ;

    // Q fragments (used as B-operand: n = query = l15)
    half8 qf[2][2];
    {
        const half_t* qpp = Qh + ((size_t)(b * NH + h) * SEQ + q0 + wm) * 64;
        #pragma unroll
        for (int mf = 0; mf < 2; mf++)
            #pragma unroll
            for (int kc = 0; kc < 2; kc++)
                qf[mf][kc] = *(const half8*)(qpp + (size_t)(mf * 16 + l15) * 64 + kc * 32 + quad * 8);
    }

    int koff[2], voff[2], lo[2];
    #pragma unroll
    for (int is = 0; is < 2; is++) {
        int s = is * 256 + tid;
        int p = s >> 3, c = (s & 7) ^ (p & 7);
        koff[is] = p * 64 + c * 8;
        voff[is] = p * SEQ + c * 8;
        lo[is]   = (is * 256 + wave * 64) * 8;
    }

    float m_i[2], l_i[2];
    m_i[0] = m_i[1] = -__builtin_inff();
    l_i[0] = l_i[1] = 0.f;
    floatx4 o[2][4] = {};

    const int ntiles = 2 * qt + 2;
    #pragma unroll
    for (int is = 0; is < 2; is++) {
        gload16(&Ks[0][lo[is]], kp + koff[is]);
        gload16(&Vs[0][lo[is]], vp + voff[is]);
    }

    const int srcA = l15 + ((quad & 1) ? 32 : 0);
    const int srcB = srcA + 16;
    const bool hiK = (quad >> 1) != 0;

    for (int kt = 0; kt < ntiles; kt++) {
        const int cur = kt & 1;
        const int kb  = kt * 64;
        __syncthreads();                       // buf[cur] loads complete (all waves)
        if (kt + 1 < ntiles) {
            const int kb2 = (kt + 1) * 64;
            #pragma unroll
            for (int is = 0; is < 2; is++) {
                gload16(&Ks[cur ^ 1][lo[is]], kp + (size_t)kb2 * 64 + koff[is]);
                gload16(&Vs[cur ^ 1][lo[is]], vp + kb2 + voff[is]);
            }
        }

        if (kb <= q0 + wm + 31) {
            // S^T = K @ Q^T : rows = keys, cols = queries
            floatx4 sa[2][4] = {};
            #pragma unroll
            for (int kc = 0; kc < 2; kc++)
                #pragma unroll
                for (int kf = 0; kf < 4; kf++) {
                    int row = kf * 16 + l15;
                    int sc = ((kc * 4 + quad) ^ (row & 7));
                    half8 kfr = *(const half8*)&Ks[cur][row * 64 + sc * 8];
                    sa[0][kf] = __builtin_amdgcn_mfma_f32_16x16x32_f16(kfr, qf[0][kc], sa[0][kf], 0, 0, 0);
                    sa[1][kf] = __builtin_amdgcn_mfma_f32_16x16x32_f16(kfr, qf[1][kc], sa[1][kf], 0, 0, 0);
                }

            if (kb + 63 > q0 + wm) {   // diagonal tile: mask key > query
                #pragma unroll
                for (int kf = 0; kf < 4; kf++)
                    #pragma unroll
                    for (int r = 0; r < 4; r++) {
                        int key = kb + kf * 16 + quad * 4 + r;
                        if (key > q0 + wm + l15)      sa[0][kf][r] = -__builtin_inff();
                        if (key > q0 + wm + 16 + l15) sa[1][kf][r] = -__builtin_inff();
                    }
            }

            int eh[2][4][2];   // packed half2 exp values
            float alpha[2];
            #pragma unroll
            for (int mf = 0; mf < 2; mf++) {
                float mt = sa[mf][0][0];
                #pragma unroll
                for (int kf = 0; kf < 4; kf++)
                    #pragma unroll
                    for (int r = 0; r < 4; r++) mt = fmaxf(mt, sa[mf][kf][r]);
                mt = fmaxf(mt, __shfl_xor(mt, 16));
                mt = fmaxf(mt, __shfl_xor(mt, 32));
                float mn = fmaxf(m_i[mf], mt);
                alpha[mf] = exp2f(m_i[mf] - mn);
                m_i[mf] = mn;
                float rs = 0.f;
                #pragma unroll
                for (int kf = 0; kf < 4; kf++) {
                    float e0 = exp2f(sa[mf][kf][0] - mn);
                    float e1 = exp2f(sa[mf][kf][1] - mn);
                    float e2 = exp2f(sa[mf][kf][2] - mn);
                    float e3 = exp2f(sa[mf][kf][3] - mn);
                    rs += (e0 + e1) + (e2 + e3);
                    H2I p01, p23;
                    p01.h = __builtin_amdgcn_cvt_pkrtz(e0, e1);
                    p23.h = __builtin_amdgcn_cvt_pkrtz(e2, e3);
                    eh[mf][kf][0] = p01.i;
                    eh[mf][kf][1] = p23.i;
                }
                rs += __shfl_xor(rs, 16);
                rs += __shfl_xor(rs, 32);
                l_i[mf] = l_i[mf] * alpha[mf] + rs;
                #pragma unroll
                for (int nf = 0; nf < 4; nf++)
                    #pragma unroll
                    for (int r = 0; r < 4; r++) o[mf][nf][r] *= alpha[mf];
            }

            // O^T += V^T @ P^T  (P^T B-frag via in-register shuffles)
            #pragma unroll
            for (int kc = 0; kc < 2; kc++) {
                H8U pf[2];
                #pragma unroll
                for (int mf = 0; mf < 2; mf++) {
                    int a0 = __shfl(eh[mf][2 * kc][0],     srcA);
                    int a1 = __shfl(eh[mf][2 * kc][1],     srcA);
                    int b0 = __shfl(eh[mf][2 * kc + 1][0], srcA);
                    int b1 = __shfl(eh[mf][2 * kc + 1][1], srcA);
                    int c0 = __shfl(eh[mf][2 * kc][0],     srcB);
                    int c1 = __shfl(eh[mf][2 * kc][1],     srcB);
                    int d0 = __shfl(eh[mf][2 * kc + 1][0], srcB);
                    int d1 = __shfl(eh[mf][2 * kc + 1][1], srcB);
                    pf[mf].u[0] = hiK ? b0 : a0;
                    pf[mf].u[1] = hiK ? b1 : a1;
                    pf[mf].u[2] = hiK ? d0 : c0;
                    pf[mf].u[3] = hiK ? d1 : c1;
                }
                #pragma unroll
                for (int nf = 0; nf < 4; nf++) {
                    int row = nf * 16 + l15;
                    int sc = ((kc * 4 + quad) ^ (row & 7));
                    half8 vf = *(const half8*)&Vs[cur][row * 64 + sc * 8];
                    o[0][nf] = __builtin_amdgcn_mfma_f32_16x16x32_f16(vf, pf[0].h, o[0][nf], 0, 0, 0);
                    o[1][nf] = __builtin_amdgcn_mfma_f32_16x16x32_f16(vf, pf[1].h, o[1][nf], 0, 0, 0);
                }
            }
        }
    }

    // epilogue: O^T cols = queries; d = 16nf + 4quad + r -> half4 stores
    #pragma unroll
    for (int mf = 0; mf < 2; mf++) {
        float inv = 1.0f / l_i[mf];
        int s = q0 + wm + mf * 16 + l15;
        half_t* op = ctx + (size_t)(b * SEQ + s) * DOUT + h * 64 + quad * 4;
        #pragma unroll
        for (int nf = 0; nf < 4; nf++) {
            half4 hv;
            hv[0] = (half_t)(o[mf][nf][0] * inv);
            hv[1] = (half_t)(o[mf][nf][1] * inv);
            hv[2] = (half_t)(o[mf][nf][2] * inv);
            hv[3] = (half_t)(o[mf][nf][3] * inv);
            *(half4*)(op + nf * 16) = hv;
        }
    }
}

// ---------------------------------------------------------------- launch
extern "C" void kernel_launch(void* const* d_in, const int* in_sizes, int n_in,
                              void* d_out, int out_size, void* d_ws, size_t ws_size,
                              hipStream_t stream) {
    const float* x    = (const float*)d_in[0];
    const float* cosb = (const float*)d_in[1];
    const float* sinb = (const float*)d_in[2];
    const float* Wq   = (const float*)d_in[4];
    const float* Wk   = (const float*)d_in[5];
    const float* Wv   = (const float*)d_in[6];
    const float* Wo   = (const float*)d_in[7];
    float* out = (float*)d_out;

    const size_t M  = (size_t)BB * SEQ;   // 4096
    const size_t nX = M * DIN;

    char* ws = (char*)d_ws;
    const size_t MB = 1048576;
    half_t* xh     = (half_t*)(ws);              // 16 MiB
    half_t* WqkvT  = (half_t*)(ws + 16 * MB);    // 12 MiB  [3072][2048]
    half_t* WoT    = (half_t*)(ws + 28 * MB);    //  8 MiB
    half_t* Qh     = (half_t*)(ws + 36 * MB);    // 16 MiB  [b][h][s][64]
    half_t* Kh     = (half_t*)(ws + 52 * MB);    //  4 MiB  [b][g][s][64]
    half_t* Vt     = (half_t*)(ws + 56 * MB);    //  4 MiB  [b][g][d][SEQ]
    half_t* ctxh   = (half_t*)(ws + 60 * MB);    // 16 MiB  [b][s][h*64]

    // casts / weight transposes (Wq|Wk|Wv fused into one [3072][2048] Bt)
    cast_f2h<<<(nX / 4) / 256, 256, 0, stream>>>(x, xh, nX / 4);
    tcast<<<dim3(64, 64), 256, 0, stream>>>(Wq, WqkvT, DIN, DOUT);
    tcast<<<dim3(16, 64), 256, 0, stream>>>(Wk, WqkvT + (size_t)2048 * 2048, DIN, 512);
    tcast<<<dim3(16, 64), 256, 0, stream>>>(Wv, WqkvT + (size_t)2560 * 2048, DIN, 512);
    tcast<<<dim3(64, 64), 256, 0, stream>>>(Wo, WoT, DOUT, DOUT);

    // fused QKV projection + RoPE + relayout
    gemm_qkv<<<dim3(3072 / 128, M / 128), 256, 0, stream>>>(xh, WqkvT, cosb, sinb, Qh, Kh, Vt);

    // attention
    attn<<<BB * NH * (SEQ / 128), 256, 0, stream>>>(Qh, Kh, Vt, ctxh);

    // output projection (f32 out)
    gemm_tn_f<<<dim3(DOUT / 128, M / 128), 256, 0, stream>>>(ctxh, WoT, out, M, DOUT, DIN);
}

// Round 6
// 359.419 us; speedup vs baseline: 1.0304x; 1.0304x over previous
//
#include <hip/hip_runtime.h>
#include <hip/hip_fp16.h>

#define SEQ    2048
#define DIN    2048
#define DOUT   2048
#define NH     32
#define NKV    8
#define HD     64
#define BB     2

typedef _Float16 half_t;
typedef __attribute__((ext_vector_type(8))) _Float16 half8;
typedef __attribute__((ext_vector_type(4))) _Float16 half4;
typedef __attribute__((ext_vector_type(2))) __fp16   fp16x2;   // cvt_pkrtz native type
typedef __attribute__((ext_vector_type(4))) float    floatx4;

union H8U { half8 h; int u[4]; };
union H2I { fp16x2 h; int i; };

#if __has_builtin(__builtin_amdgcn_exp2f)
#define EXP2F(x) __builtin_amdgcn_exp2f(x)
#else
#define EXP2F(x) __expf((x) * 0.6931471805599453f)
#endif

// async 16B global->LDS (wave-uniform LDS base + lane*16)
__device__ __forceinline__ void gload16(void* l, const void* g) {
    __builtin_amdgcn_global_load_lds(
        (const __attribute__((address_space(1))) void*)g,
        (__attribute__((address_space(3))) void*)l, 16, 0, 0);
}

// ---------------------------------------------------------------- cast f32->f16
__global__ void cast_f2h(const float* __restrict__ in, half_t* __restrict__ out, int n4) {
    int i = blockIdx.x * blockDim.x + threadIdx.x;
    if (i < n4) {
        float4 v = ((const float4*)in)[i];
        half4 h;
        h[0] = (half_t)v.x; h[1] = (half_t)v.y; h[2] = (half_t)v.z; h[3] = (half_t)v.w;
        ((half4*)out)[i] = h;
    }
}

// ---------------------------------------------------------------- transpose+cast: f32 [Kd][Nd] -> f16 [Nd][Kd]
__global__ __launch_bounds__(256) void tcast(const float* __restrict__ in, half_t* __restrict__ out,
                                             int Kd, int Nd) {
    __shared__ float T[32][33];
    int x0 = blockIdx.x * 32, y0 = blockIdx.y * 32;
    int tx = threadIdx.x & 31, ty = threadIdx.x >> 5;
    #pragma unroll
    for (int j = 0; j < 4; j++)
        T[ty + j * 8][tx] = in[(size_t)(y0 + ty + j * 8) * Nd + x0 + tx];
    __syncthreads();
    #pragma unroll
    for (int j = 0; j < 4; j++)
        out[(size_t)(x0 + ty + j * 8) * Kd + y0 + tx] = (half_t)T[tx][ty + j * 8];
}

// ---------------------------------------------------------------- fused QKV GEMM + K-RoPE + relayout
// C = xh[4096x2048] @ WqkvT[3072x2048]^T ; epilogue routes each wave's 64-col head:
//   cols <2048  : plain store -> Qh [b][h][s][64]   (RoPE applied later in attn)
//   2048..2559  : RoPE        -> Kh [b][g][s][64]
//   2560..3071  : transpose   -> Vt [b][g][d][SEQ]
__global__ __launch_bounds__(256) void gemm_qkv(
    const half_t* __restrict__ A, const half_t* __restrict__ Bt,
    const float* __restrict__ cosb, const float* __restrict__ sinb,
    half_t* __restrict__ Qh, half_t* __restrict__ Kh, half_t* __restrict__ Vt)
{
    __shared__ half_t As[4096];
    __shared__ half_t Bs[4096];
    const int K = DIN;
    int tid = threadIdx.x, wave = tid >> 6, lane = tid & 63;
    int quad = lane >> 4, l15 = lane & 15;
    int m0 = blockIdx.y * 128, n0 = blockIdx.x * 128;
    int wm = (wave >> 1) * 64, wn = (wave & 1) * 64;
    floatx4 acc[4][4] = {};

    int srow[2], skoff[2], sldso[2];
    #pragma unroll
    for (int is = 0; is < 2; is++) {
        int s = is * 256 + tid;
        int p = s >> 3, sc = s & 7;
        int c = sc ^ (p & 7);
        srow[is]  = 2 * p + (c >> 2);
        skoff[is] = (c & 3) * 8;
        sldso[is] = (is * 256 + wave * 64) * 8;
    }
    for (int k0 = 0; k0 < K; k0 += 32) {
        __syncthreads();
        #pragma unroll
        for (int is = 0; is < 2; is++) {
            gload16(&As[sldso[is]], A  + (size_t)(m0 + srow[is]) * K + k0 + skoff[is]);
            gload16(&Bs[sldso[is]], Bt + (size_t)(n0 + srow[is]) * K + k0 + skoff[is]);
        }
        __syncthreads();
        half8 af[4], bf[4];
        #pragma unroll
        for (int i = 0; i < 4; i++) {
            int r = wm + i * 16 + l15, p = r >> 1;
            int sc = (((r & 1) * 4 + quad) ^ (p & 7));
            af[i] = *(const half8*)&As[p * 64 + sc * 8];
            int rn = wn + i * 16 + l15, pn = rn >> 1;
            int scn = (((rn & 1) * 4 + quad) ^ (pn & 7));
            bf[i] = *(const half8*)&Bs[pn * 64 + scn * 8];
        }
        #pragma unroll
        for (int i = 0; i < 4; i++)
            #pragma unroll
            for (int j = 0; j < 4; j++)
                acc[i][j] = __builtin_amdgcn_mfma_f32_16x16x32_f16(af[i], bf[j], acc[i][j], 0, 0, 0);
    }

    // -------- epilogue: wave-uniform head routing
    const int headg = (n0 + wn) >> 6;          // 0..47
    const int b = m0 >> 11;                    // block never straddles batch
    const int s_base = (m0 & 2047) + wm + quad * 4;

    if (headg < 32) {                          // Q: plain head-major store
        half_t* outp = Qh + (size_t)(b * NH + headg) * SEQ * 64;
        #pragma unroll
        for (int i = 0; i < 4; i++)
            #pragma unroll
            for (int j = 0; j < 4; j++) {
                int d = j * 16 + l15;
                #pragma unroll
                for (int r = 0; r < 4; r++)
                    outp[(size_t)(s_base + i * 16 + r) * 64 + d] = (half_t)acc[i][j][r];
            }
    } else if (headg < 40) {                   // K: RoPE
        half_t* outp = Kh + (size_t)(b * NKV + (headg - 32)) * SEQ * 64;
        #pragma unroll
        for (int i = 0; i < 4; i++)
            #pragma unroll
            for (int r = 0; r < 4; r++) {
                int s = s_base + i * 16 + r;
                #pragma unroll
                for (int j = 0; j < 2; j++) {
                    int d = j * 16 + l15;
                    float x1 = acc[i][j][r], x2 = acc[i][j + 2][r];
                    float c1 = cosb[s * 64 + d],      s1 = sinb[s * 64 + d];
                    float c2 = cosb[s * 64 + d + 32], s2 = sinb[s * 64 + d + 32];
                    outp[(size_t)s * 64 + d]      = (half_t)(x1 * c1 - x2 * s1);
                    outp[(size_t)s * 64 + d + 32] = (half_t)(x2 * c2 + x1 * s2);
                }
            }
    } else {                                   // V: transpose to [d][s]
        half_t* vtp = Vt + (size_t)(b * NKV + (headg - 40)) * 64 * SEQ;
        #pragma unroll
        for (int i = 0; i < 4; i++) {
            int s = s_base + i * 16;
            #pragma unroll
            for (int j = 0; j < 4; j++) {
                int d = j * 16 + l15;
                half4 hv;
                hv[0] = (half_t)acc[i][j][0];
                hv[1] = (half_t)acc[i][j][1];
                hv[2] = (half_t)acc[i][j][2];
                hv[3] = (half_t)acc[i][j][3];
                *(half4*)(vtp + (size_t)d * SEQ + s) = hv;
            }
        }
    }
}

// ---------------------------------------------------------------- GEMM (m97 structure), f32 out
__global__ __launch_bounds__(256) void gemm_tn_f(
    const half_t* __restrict__ A, const half_t* __restrict__ Bt,
    float* __restrict__ C, int M, int N, int K)
{
    __shared__ half_t As[4096];
    __shared__ half_t Bs[4096];
    int tid = threadIdx.x, wave = tid >> 6, lane = tid & 63;
    int quad = lane >> 4, l15 = lane & 15;
    int m0 = blockIdx.y * 128, n0 = blockIdx.x * 128;
    int wm = (wave >> 1) * 64, wn = (wave & 1) * 64;
    floatx4 acc[4][4] = {};
    int srow[2], skoff[2], sldso[2];
    #pragma unroll
    for (int is = 0; is < 2; is++) {
        int s = is * 256 + tid;
        int p = s >> 3, sc = s & 7;
        int c = sc ^ (p & 7);
        srow[is]  = 2 * p + (c >> 2);
        skoff[is] = (c & 3) * 8;
        sldso[is] = (is * 256 + wave * 64) * 8;
    }
    for (int k0 = 0; k0 < K; k0 += 32) {
        __syncthreads();
        #pragma unroll
        for (int is = 0; is < 2; is++) {
            gload16(&As[sldso[is]], A  + (size_t)(m0 + srow[is]) * K + k0 + skoff[is]);
            gload16(&Bs[sldso[is]], Bt + (size_t)(n0 + srow[is]) * K + k0 + skoff[is]);
        }
        __syncthreads();
        half8 af[4], bf[4];
        #pragma unroll
        for (int i = 0; i < 4; i++) {
            int r = wm + i * 16 + l15, p = r >> 1;
            int sc = (((r & 1) * 4 + quad) ^ (p & 7));
            af[i] = *(const half8*)&As[p * 64 + sc * 8];
            int rn = wn + i * 16 + l15, pn = rn >> 1;
            int scn = (((rn & 1) * 4 + quad) ^ (pn & 7));
            bf[i] = *(const half8*)&Bs[pn * 64 + scn * 8];
        }
        #pragma unroll
        for (int i = 0; i < 4; i++)
            #pragma unroll
            for (int j = 0; j < 4; j++)
                acc[i][j] = __builtin_amdgcn_mfma_f32_16x16x32_f16(af[i], bf[j], acc[i][j], 0, 0, 0);
    }
    #pragma unroll
    for (int i = 0; i < 4; i++) {
        int row = m0 + wm + i * 16 + quad * 4;
        #pragma unroll
        for (int j = 0; j < 4; j++) {
            int col = n0 + wn + j * 16 + l15;
            #pragma unroll
            for (int r = 0; r < 4; r++)
                C[(size_t)(row + r) * N + col] = acc[i][j][r];
        }
    }
}

// ---------------------------------------------------------------- causal GQA flash attention (S^T layout)
// 256 thr = 4 waves; 128 queries/block; 64-key tiles, double-buffered async staging.
// Q-RoPE + scale(0.125*log2e) applied at Q-load; softmax in base-2 (v_exp_f32).
__global__ __launch_bounds__(256, 4) void attn(
    const half_t* __restrict__ Qh, const half_t* __restrict__ Kh,
    const half_t* __restrict__ Vt, const float* __restrict__ cosb,
    const float* __restrict__ sinb, half_t* __restrict__ ctx)
{
    __shared__ half_t Ks[2][4096];
    __shared__ half_t Vs[2][4096];

    const int tid = threadIdx.x, wave = tid >> 6, lane = tid & 63;
    const int quad = lane >> 4, l15 = lane & 15;
    const int bid = blockIdx.x;
    // balanced schedule: each CU-slot quadruple sums to 30 tiles-of-qt
    const int k  = bid >> 8;           // dispatch round 0..3
    const int u  = bid & 255;
    const int q2 = u & 3;
    const int bh = u >> 2;             // 0..63
    const int qt = (k == 0) ? 15 - 2 * q2 : (k == 1) ? 2 * q2
                 : (k == 2) ? 14 - 2 * q2 : 2 * q2 + 1;
    const int b  = bh >> 5;
    const int h  = bh & 31;
    const int g  = h >> 2;
    const int q0 = qt * 128;
    const int wm = wave * 32;

    const half_t* kp = Kh + (size_t)(b * NKV + g) * SEQ * 64;
    const half_t* vp = Vt + (size_t)(b * NKV + g) * 64 * SEQ;

    // Q fragments: load raw Q, apply RoPE + scale in-register (once per block)
    half8 qf[2][2];
    {
        const float sc = 0.125f * 1.44269504088896f;
        const half_t* qpp = Qh + ((size_t)(b * NH + h) * SEQ + q0 + wm) * 64;
        #pragma unroll
        for (int mf = 0; mf < 2; mf++) {
            int s = q0 + wm + mf * 16 + l15;
            const float* cp = cosb + s * 64 + quad * 8;
            const float* sp = sinb + s * 64 + quad * 8;
            half8 xa = *(const half8*)(qpp + (size_t)(mf * 16 + l15) * 64 + quad * 8);
            half8 xb = *(const half8*)(qpp + (size_t)(mf * 16 + l15) * 64 + 32 + quad * 8);
            float4 c1a = *(const float4*)(cp),      c1b = *(const float4*)(cp + 4);
            float4 s1a = *(const float4*)(sp),      s1b = *(const float4*)(sp + 4);
            float4 c2a = *(const float4*)(cp + 32), c2b = *(const float4*)(cp + 36);
            float4 s2a = *(const float4*)(sp + 32), s2b = *(const float4*)(sp + 36);
            const float* c1 = (const float*)&c1a;  // c1a,c1b contiguous? no — index piecewise
            #pragma unroll
            for (int t = 0; t < 8; t++) {
                float cc1 = (t < 4) ? ((const float*)&c1a)[t] : ((const float*)&c1b)[t - 4];
                float ss1 = (t < 4) ? ((const float*)&s1a)[t] : ((const float*)&s1b)[t - 4];
                float cc2 = (t < 4) ? ((const float*)&c2a)[t] : ((const float*)&c2b)[t - 4];
                float ss2 = (t < 4) ? ((const float*)&s2a)[t] : ((const float*)&s2b)[t - 4];
                float x1 = (float)xa[t], x2 = (float)xb[t];
                qf[mf][0][t] = (half_t)((x1 * cc1 - x2 * ss1) * sc);
                qf[mf][1][t] = (half_t)((x2 * cc2 + x1 * ss2) * sc);
            }
            (void)c1;
        }
    }

    int koff[2], voff[2], lo[2];
    #pragma unroll
    for (int is = 0; is < 2; is++) {
        int s = is * 256 + tid;
        int p = s >> 3, c = (s & 7) ^ (p & 7);
        koff[is] = p * 64 + c * 8;
        voff[is] = p * SEQ + c * 8;
        lo[is]   = (is * 256 + wave * 64) * 8;
    }

    float m_i[2], l_i[2];
    m_i[0] = m_i[1] = -__builtin_inff();
    l_i[0] = l_i[1] = 0.f;
    floatx4 o[2][4] = {};

    const int ntiles = 2 * qt + 2;
    #pragma unroll
    for (int is = 0; is < 2; is++) {
        gload16(&Ks[0][lo[is]], kp + koff[is]);
        gload16(&Vs[0][lo[is]], vp + voff[is]);
    }

    const int srcA = l15 + ((quad & 1) ? 32 : 0);
    const int srcB = srcA + 16;
    const bool hiK = (quad >> 1) != 0;

    for (int kt = 0; kt < ntiles; kt++) {
        const int cur = kt & 1;
        const int kb  = kt * 64;
        __syncthreads();                       // buf[cur] loads complete (all waves)
        if (kt + 1 < ntiles) {
            const int kb2 = (kt + 1) * 64;
            #pragma unroll
            for (int is = 0; is < 2; is++) {
                gload16(&Ks[cur ^ 1][lo[is]], kp + (size_t)kb2 * 64 + koff[is]);
                gload16(&Vs[cur ^ 1][lo[is]], vp + kb2 + voff[is]);
            }
        }

        if (kb <= q0 + wm + 31) {
            // S^T = K @ Q^T : rows = keys, cols = queries
            floatx4 sa[2][4] = {};
            #pragma unroll
            for (int kc = 0; kc < 2; kc++)
                #pragma unroll
                for (int kf = 0; kf < 4; kf++) {
                    int row = kf * 16 + l15;
                    int sc = ((kc * 4 + quad) ^ (row & 7));
                    half8 kfr = *(const half8*)&Ks[cur][row * 64 + sc * 8];
                    sa[0][kf] = __builtin_amdgcn_mfma_f32_16x16x32_f16(kfr, qf[0][kc], sa[0][kf], 0, 0, 0);
                    sa[1][kf] = __builtin_amdgcn_mfma_f32_16x16x32_f16(kfr, qf[1][kc], sa[1][kf], 0, 0, 0);
                }

            if (kb + 63 > q0 + wm) {   // diagonal tile: mask key > query
                #pragma unroll
                for (int kf = 0; kf < 4; kf++)
                    #pragma unroll
                    for (int r = 0; r < 4; r++) {
                        int key = kb + kf * 16 + quad * 4 + r;
                        if (key > q0 + wm + l15)      sa[0][kf][r] = -__builtin_inff();
                        if (key > q0 + wm + 16 + l15) sa[1][kf][r] = -__builtin_inff();
                    }
            }

            int eh[2][4][2];   // packed half2 exp values
            float alpha[2];
            #pragma unroll
            for (int mf = 0; mf < 2; mf++) {
                float mt = sa[mf][0][0];
                #pragma unroll
                for (int kf = 0; kf < 4; kf++)
                    #pragma unroll
                    for (int r = 0; r < 4; r++) mt = fmaxf(mt, sa[mf][kf][r]);
                mt = fmaxf(mt, __shfl_xor(mt, 16));
                mt = fmaxf(mt, __shfl_xor(mt, 32));
                float mn = fmaxf(m_i[mf], mt);
                alpha[mf] = EXP2F(m_i[mf] - mn);
                m_i[mf] = mn;
                float rs = 0.f;
                #pragma unroll
                for (int kf = 0; kf < 4; kf++) {
                    float e0 = EXP2F(sa[mf][kf][0] - mn);
                    float e1 = EXP2F(sa[mf][kf][1] - mn);
                    float e2 = EXP2F(sa[mf][kf][2] - mn);
                    float e3 = EXP2F(sa[mf][kf][3] - mn);
                    rs += (e0 + e1) + (e2 + e3);
                    H2I p01, p23;
                    p01.h = __builtin_amdgcn_cvt_pkrtz(e0, e1);
                    p23.h = __builtin_amdgcn_cvt_pkrtz(e2, e3);
                    eh[mf][kf][0] = p01.i;
                    eh[mf][kf][1] = p23.i;
                }
                rs += __shfl_xor(rs, 16);
                rs += __shfl_xor(rs, 32);
                l_i[mf] = l_i[mf] * alpha[mf] + rs;
                #pragma unroll
                for (int nf = 0; nf < 4; nf++)
                    #pragma unroll
                    for (int r = 0; r < 4; r++) o[mf][nf][r] *= alpha[mf];
            }

            // O^T += V^T @ P^T  (P^T B-frag via in-register shuffles)
            #pragma unroll
            for (int kc = 0; kc < 2; kc++) {
                H8U pf[2];
                #pragma unroll
                for (int mf = 0; mf < 2; mf++) {
                    int a0 = __shfl(eh[mf][2 * kc][0],     srcA);
                    int a1 = __shfl(eh[mf][2 * kc][1],     srcA);
                    int b0 = __shfl(eh[mf][2 * kc + 1][0], srcA);
                    int b1 = __shfl(eh[mf][2 * kc + 1][1], srcA);
                    int c0 = __shfl(eh[mf][2 * kc][0],     srcB);
                    int c1 = __shfl(eh[mf][2 * kc][1],     srcB);
                    int d0 = __shfl(eh[mf][2 * kc + 1][0], srcB);
                    int d1 = __shfl(eh[mf][2 * kc + 1][1], srcB);
                    pf[mf].u[0] = hiK ? b0 : a0;
                    pf[mf].u[1] = hiK ? b1 : a1;
                    pf[mf].u[2] = hiK ? d0 : c0;
                    pf[mf].u[3] = hiK ? d1 : c1;
                }
                #pragma unroll
                for (int nf = 0; nf < 4; nf++) {
                    int row = nf * 16 + l15;
                    int sc = ((kc * 4 + quad) ^ (row & 7));
                    half8 vf = *(const half8*)&Vs[cur][row * 64 + sc * 8];
                    o[0][nf] = __builtin_amdgcn_mfma_f32_16x16x32_f16(vf, pf[0].h, o[0][nf], 0, 0, 0);
                    o[1][nf] = __builtin_amdgcn_mfma_f32_16x16x32_f16(vf, pf[1].h, o[1][nf], 0, 0, 0);
                }
            }
        }
    }

    // epilogue: O^T cols = queries; d = 16nf + 4quad + r -> half4 stores
    #pragma unroll
    for (int mf = 0; mf < 2; mf++) {
        float inv = 1.0f / l_i[mf];
        int s = q0 + wm + mf * 16 + l15;
        half_t* op = ctx + (size_t)(b * SEQ + s) * DOUT + h * 64 + quad * 4;
        #pragma unroll
        for (int nf = 0; nf < 4; nf++) {
            half4 hv;
            hv[0] = (half_t)(o[mf][nf][0] * inv);
            hv[1] = (half_t)(o[mf][nf][1] * inv);
            hv[2] = (half_t)(o[mf][nf][2] * inv);
            hv[3] = (half_t)(o[mf][nf][3] * inv);
            *(half4*)(op + nf * 16) = hv;
        }
    }
}

// ---------------------------------------------------------------- launch
extern "C" void kernel_launch(void* const* d_in, const int* in_sizes, int n_in,
                              void* d_out, int out_size, void* d_ws, size_t ws_size,
                              hipStream_t stream) {
    const float* x    = (const float*)d_in[0];
    const float* cosb = (const float*)d_in[1];
    const float* sinb = (const float*)d_in[2];
    const float* Wq   = (const float*)d_in[4];
    const float* Wk   = (const float*)d_in[5];
    const float* Wv   = (const float*)d_in[6];
    const float* Wo   = (const float*)d_in[7];
    float* out = (float*)d_out;

    const size_t M  = (size_t)BB * SEQ;   // 4096
    const size_t nX = M * DIN;

    char* ws = (char*)d_ws;
    const size_t MB = 1048576;
    half_t* xh     = (half_t*)(ws);              // 16 MiB
    half_t* WqkvT  = (half_t*)(ws + 16 * MB);    // 12 MiB  [3072][2048]
    half_t* WoT    = (half_t*)(ws + 28 * MB);    //  8 MiB
    half_t* Qh     = (half_t*)(ws + 36 * MB);    // 16 MiB  [b][h][s][64] (raw, pre-RoPE)
    half_t* Kh     = (half_t*)(ws + 52 * MB);    //  4 MiB  [b][g][s][64] (RoPE'd)
    half_t* Vt     = (half_t*)(ws + 56 * MB);    //  4 MiB  [b][g][d][SEQ]
    half_t* ctxh   = (half_t*)(ws + 60 * MB);    // 16 MiB  [b][s][h*64]

    // casts / weight transposes (Wq|Wk|Wv fused into one [3072][2048] Bt)
    cast_f2h<<<(nX / 4) / 256, 256, 0, stream>>>(x, xh, nX / 4);
    tcast<<<dim3(64, 64), 256, 0, stream>>>(Wq, WqkvT, DIN, DOUT);
    tcast<<<dim3(16, 64), 256, 0, stream>>>(Wk, WqkvT + (size_t)2048 * 2048, DIN, 512);
    tcast<<<dim3(16, 64), 256, 0, stream>>>(Wv, WqkvT + (size_t)2560 * 2048, DIN, 512);
    tcast<<<dim3(64, 64), 256, 0, stream>>>(Wo, WoT, DOUT, DOUT);

    // fused QKV projection + K-RoPE + relayout
    gemm_qkv<<<dim3(3072 / 128, M / 128), 256, 0, stream>>>(xh, WqkvT, cosb, sinb, Qh, Kh, Vt);

    // attention (Q-RoPE fused at load)
    attn<<<BB * NH * (SEQ / 128), 256, 0, stream>>>(Qh, Kh, Vt, cosb, sinb, ctxh);

    // output projection (f32 out)
    gemm_tn_f<<<dim3(DOUT / 128, M / 128), 256, 0, stream>>>(ctxh, WoT, out, M, DOUT, DIN);
}